// Round 1
// baseline (373.505 us; speedup 1.0000x reference)
//
#include <hip/hip_runtime.h>
#include <math.h>

#define MC   2048
#define DD   128
#define BB   64
#define LL   16
#define NOBJ 128
#define FDIM 512
#define NN   (MC + NOBJ)
#define TEMPC 3.0f
#define THC   0.8f
#define POSC  10.0f
#define NEGC  (-10.0f)
#define EPSC  1e-8f
#define T     1024
#define NINF  (-3.402823466e38f)

// ---------------- Kernel A: objects = scene @ W_feat + b_feat ----------------
// grid (4, B); blockIdx.x: mt=(x>>1)*64 obj tile, nt=(x&1)*64 d tile. 256 thr, 4x4 micro.
__global__ __launch_bounds__(256) void gemm_objects(
        const float* __restrict__ scene, const float* __restrict__ W,
        const float* __restrict__ bias, float* __restrict__ obj) {
    __shared__ float sA[64][68];   // sA[k][o]
    __shared__ float sB[64][68];   // sB[k][d]
    const int b  = blockIdx.y;
    const int mt = (blockIdx.x >> 1) * 64;
    const int nt = (blockIdx.x & 1) * 64;
    const int tid = threadIdx.x;
    const int tx = tid & 15, ty = tid >> 4;
    float acc[4][4] = {{0.f,0.f,0.f,0.f},{0.f,0.f,0.f,0.f},{0.f,0.f,0.f,0.f},{0.f,0.f,0.f,0.f}};
    const float* sc = scene + (size_t)b * NOBJ * FDIM;
    for (int k0 = 0; k0 < FDIM; k0 += 64) {
        {   // scene tile -> sA (transposed)
            const int o  = tid >> 2;
            const int ks = (tid & 3) * 16;
            const float4* src = (const float4*)(sc + (size_t)(mt + o) * FDIM + k0 + ks);
            #pragma unroll
            for (int j4 = 0; j4 < 4; j4++) {
                float4 v = src[j4];
                sA[ks + j4*4 + 0][o] = v.x;
                sA[ks + j4*4 + 1][o] = v.y;
                sA[ks + j4*4 + 2][o] = v.z;
                sA[ks + j4*4 + 3][o] = v.w;
            }
        }
        {   // W tile -> sB
            const int kk = tid >> 2;
            const int dq = (tid & 3) * 16;
            const float4* src = (const float4*)(W + (size_t)(k0 + kk) * DD + nt + dq);
            float4* dst = (float4*)&sB[kk][dq];
            #pragma unroll
            for (int j4 = 0; j4 < 4; j4++) dst[j4] = src[j4];
        }
        __syncthreads();
        #pragma unroll 8
        for (int kk = 0; kk < 64; kk++) {
            float4 a4 = *(const float4*)&sA[kk][ty * 4];
            float4 b4 = *(const float4*)&sB[kk][tx * 4];
            float av[4] = {a4.x, a4.y, a4.z, a4.w};
            float bv[4] = {b4.x, b4.y, b4.z, b4.w};
            #pragma unroll
            for (int i = 0; i < 4; i++)
                #pragma unroll
                for (int j = 0; j < 4; j++)
                    acc[i][j] = fmaf(av[i], bv[j], acc[i][j]);
        }
        __syncthreads();
    }
    #pragma unroll
    for (int i = 0; i < 4; i++) {
        const int o = mt + ty * 4 + i;
        float4 r;
        r.x = acc[i][0] + bias[nt + tx*4 + 0];
        r.y = acc[i][1] + bias[nt + tx*4 + 1];
        r.z = acc[i][2] + bias[nt + tx*4 + 2];
        r.w = acc[i][3] + bias[nt + tx*4 + 3];
        *(float4*)(obj + ((size_t)b * NOBJ + o) * DD + nt + tx*4) = r;
    }
}

// ---------------- Kernel B: row L2 norms (concepts + objects) ----------------
__global__ __launch_bounds__(256) void row_norms(
        const float* __restrict__ ct, const float* __restrict__ obj,
        float* __restrict__ cnorm, float* __restrict__ onorm) {
    const int wid = threadIdx.x >> 6, lane = threadIdx.x & 63;
    const int r = blockIdx.x * 4 + wid;
    const int NROWS = MC + BB * NOBJ;
    if (r >= NROWS) return;
    const float* row = (r < MC) ? (ct + (size_t)r * DD) : (obj + (size_t)(r - MC) * DD);
    float x = row[lane], y = row[lane + 64];
    float ss = x * x + y * y;
    #pragma unroll
    for (int off = 32; off; off >>= 1) ss += __shfl_xor(ss, off, 64);
    if (lane == 0) {
        if (r < MC) cnorm[r] = sqrtf(ss);
        else        onorm[r - MC] = sqrtf(ss);
    }
}

// ---------------- helpers ----------------
__device__ __forceinline__ float block_reduce_max(float v, float* red, int lane, int wid) {
    #pragma unroll
    for (int off = 32; off; off >>= 1) v = fmaxf(v, __shfl_xor(v, off, 64));
    if (lane == 0) red[wid] = v;
    __syncthreads();
    float r = red[0];
    #pragma unroll
    for (int w = 1; w < 16; w++) r = fmaxf(r, red[w]);
    __syncthreads();
    return r;
}

__device__ __forceinline__ float block_reduce_sum(float v, float* red, int lane, int wid) {
    #pragma unroll
    for (int off = 32; off; off >>= 1) v += __shfl_xor(v, off, 64);
    if (lane == 0) red[wid] = v;
    __syncthreads();
    float r = red[0];
    #pragma unroll
    for (int w = 1; w < 16; w++) r += red[w];
    __syncthreads();
    return r;
}

// sim pass: for every node n compute cos-sim(node, vec); update att.
// mode==0: att[n] = min(att[n], sig); mode==1: att[n] = sig * s
__device__ __forceinline__ void sim_pass(
        const float* __restrict__ ct, const float* __restrict__ myobj,
        const float* vec, const float* nrm, float* att,
        float vn, int mode, float s, int tid) {
    const int sub  = tid & 7;     // 8 lanes cooperate on one row (16 floats each)
    const int slot = tid >> 3;    // 0..127
    for (int n = slot; n < NN; n += 128) {
        const float* row = (n < MC) ? (ct + (size_t)n * DD)
                                    : (myobj + (size_t)(n - MC) * DD);
        float dp = 0.f;
        #pragma unroll
        for (int i = 0; i < 4; i++) {
            const float4 rv = *(const float4*)(row + sub * 16 + i * 4);
            const float4 vv = *(const float4*)(vec + sub * 16 + i * 4);
            dp = fmaf(rv.x, vv.x, dp);
            dp = fmaf(rv.y, vv.y, dp);
            dp = fmaf(rv.z, vv.z, dp);
            dp = fmaf(rv.w, vv.w, dp);
        }
        dp += __shfl_xor(dp, 1, 64);
        dp += __shfl_xor(dp, 2, 64);
        dp += __shfl_xor(dp, 4, 64);
        if (sub == 0) {
            float sim = dp / (fmaxf(nrm[n], EPSC) * vn);
            float g = 1.f / (1.f + expf(-(sim - THC) * TEMPC));
            att[n] = mode ? (g * s) : fminf(att[n], g);
        }
    }
}

// ---------------- Kernel C: per-sample program scan ----------------
__global__ __launch_bounds__(1024) void scan_exec(
        const float* __restrict__ ct, const float* __restrict__ rt,
        const int* __restrict__ program, const float* __restrict__ obj,
        const float* __restrict__ cnorm, const float* __restrict__ onorm,
        float* __restrict__ out, float* __restrict__ hist) {
    const int b    = blockIdx.x;
    const int tid  = threadIdx.x;
    const int lane = tid & 63, wid = tid >> 6;
    __shared__ __align__(16) float att[NN];
    __shared__ __align__(16) float nrm[NN];
    __shared__ __align__(16) float vec[DD];       // cvec or trans
    __shared__ __align__(16) float gv[DD];        // gather
    __shared__ __align__(16) float part[32 * DD]; // reduction partials
    __shared__ float red[16];
    const float* myobj = obj + (size_t)b * NOBJ * DD;

    for (int i = tid; i < NN; i += T) {
        att[i] = 1.0f;
        nrm[i] = (i < MC) ? cnorm[i] : onorm[b * NOBJ + (i - MC)];
    }
    __syncthreads();

    for (int step = 0; step < LL; step++) {
        const int op  = program[(b * LL + step) * 2 + 0];
        const int arg = program[(b * LL + step) * 2 + 1];

        if (op == 1) {                 // sel_obj: zero concepts
            for (int i = tid; i < MC; i += T) att[i] = 0.0f;
        } else if (op == 2) {          // sel_con: zero objects
            for (int i = MC + tid; i < NN; i += T) att[i] = 0.0f;
        } else if (op == 3) {          // verify
            if (tid < DD) vec[tid] = ct[(size_t)arg * DD + tid];
            __syncthreads();
            float vn = fmaxf(cnorm[arg], EPSC);
            sim_pass(ct, myobj, vec, nrm, att, vn, 0, 0.f, tid);
        } else if (op == 4) {          // choose (arg < MC always)
            for (int i = tid; i < MC; i += T) att[i] = (i == arg) ? 1.0f : 0.0f;
        } else if (op == 5) {          // exist
            float lm = NINF;
            for (int i = tid; i < NN; i += T) lm = fmaxf(lm, att[i]);
            float s = block_reduce_max(lm, red, lane, wid);
            float yes = s * POSC;
            float no  = POSC - yes;
            for (int i = tid; i < NN; i += T)
                att[i] = (i == 0) ? yes : ((i == 1) ? no : NEGC);
        } else if (op == 6) {          // transfer
            float lm = NINF;
            for (int i = tid; i < NN; i += T) lm = fmaxf(lm, att[i]);
            float s = block_reduce_max(lm, red, lane, wid);
            // gather[d] = sum_n att[n] * node[n][d]
            const int dq  = (tid & 31) * 4;
            const int grp = tid >> 5;
            float px = 0.f, py = 0.f, pz = 0.f, pw = 0.f;
            for (int n = grp; n < NN; n += 32) {
                float a = att[n];
                const float* row = (n < MC) ? (ct + (size_t)n * DD)
                                            : (myobj + (size_t)(n - MC) * DD);
                const float4 r = *(const float4*)(row + dq);
                px = fmaf(a, r.x, px);
                py = fmaf(a, r.y, py);
                pz = fmaf(a, r.z, pz);
                pw = fmaf(a, r.w, pw);
            }
            *(float4*)&part[grp * DD + dq] = make_float4(px, py, pz, pw);
            __syncthreads();
            if (tid < DD) {
                float g = 0.f;
                #pragma unroll
                for (int gi = 0; gi < 32; gi++) g += part[gi * DD + tid];
                gv[tid] = g;
            }
            __syncthreads();
            // trans[d'] = sum_d gather[d] * rmat[d][d']
            const float* rm = rt + (size_t)arg * (DD * DD);
            float qx = 0.f, qy = 0.f, qz = 0.f, qw = 0.f;
            for (int d = grp; d < DD; d += 32) {
                float g = gv[d];
                const float4 r = *(const float4*)(rm + (size_t)d * DD + dq);
                qx = fmaf(g, r.x, qx);
                qy = fmaf(g, r.y, qy);
                qz = fmaf(g, r.z, qz);
                qw = fmaf(g, r.w, qw);
            }
            *(float4*)&part[grp * DD + dq] = make_float4(qx, qy, qz, qw);
            __syncthreads();
            if (tid < DD) {
                float t = 0.f;
                #pragma unroll
                for (int gi = 0; gi < 32; gi++) t += part[gi * DD + tid];
                vec[tid] = t;
            }
            __syncthreads();
            if (wid == 0) {            // ||trans||
                float x = vec[lane], y = vec[lane + 64];
                float ss = x * x + y * y;
                #pragma unroll
                for (int off = 32; off; off >>= 1) ss += __shfl_xor(ss, off, 64);
                if (lane == 0) red[0] = sqrtf(ss);
            }
            __syncthreads();
            float tn = fmaxf(red[0], EPSC);
            sim_pass(ct, myobj, vec, nrm, att, tn, 1, s, tid);
        }
        // op == 0: null

        __syncthreads();
        float* hrow = hist + ((size_t)b * LL + step) * NN;
        for (int i = tid; i < NN; i += T) hrow[i] = att[i];
        __syncthreads();
    }

    // log_softmax over att[0:MC]
    float lm = NINF;
    for (int i = tid; i < MC; i += T) lm = fmaxf(lm, att[i]);
    float m = block_reduce_max(lm, red, lane, wid);
    float lse = 0.f;
    for (int i = tid; i < MC; i += T) lse += expf(att[i] - m);
    float se = block_reduce_sum(lse, red, lane, wid);
    float ls = logf(se);
    for (int i = tid; i < MC; i += T)
        out[(size_t)b * MC + i] = att[i] - m - ls;
}

extern "C" void kernel_launch(void* const* d_in, const int* in_sizes, int n_in,
                              void* d_out, int out_size, void* d_ws, size_t ws_size,
                              hipStream_t stream) {
    const float* scene = (const float*)d_in[0];
    const int*   prog  = (const int*)d_in[1];
    const float* ct    = (const float*)d_in[2];
    const float* rt    = (const float*)d_in[3];
    const float* W     = (const float*)d_in[4];
    const float* bias  = (const float*)d_in[5];

    float* out  = (float*)d_out;
    float* hist = out + (size_t)BB * MC;

    float* obj   = (float*)d_ws;                    // B*NOBJ*D floats
    float* cnorm = obj + (size_t)BB * NOBJ * DD;    // MC floats
    float* onorm = cnorm + MC;                      // B*NOBJ floats

    gemm_objects<<<dim3(4, BB), 256, 0, stream>>>(scene, W, bias, obj);
    row_norms<<<dim3((MC + BB * NOBJ) / 4), 256, 0, stream>>>(ct, obj, cnorm, onorm);
    scan_exec<<<dim3(BB), 1024, 0, stream>>>(ct, rt, prog, obj, cnorm, onorm, out, hist);
}

// Round 2
// 338.378 us; speedup vs baseline: 1.1038x; 1.1038x over previous
//
#include <hip/hip_runtime.h>
#include <math.h>

#define MC   2048
#define DD   128
#define BB   64
#define LL   16
#define NOBJ 128
#define FDIM 512
#define NN   (MC + NOBJ)
#define TEMPC 3.0f
#define THC   0.8f
#define POSC  10.0f
#define NEGC  (-10.0f)
#define EPSC  1e-8f
#define T     1024
#define NARG 8
#define NINF  (-3.402823466e38f)

typedef unsigned short ushort_t;

__device__ __forceinline__ float bfu(unsigned int low16) {
    union { unsigned int i; float f; } v; v.i = low16 << 16; return v.f;
}
__device__ __forceinline__ unsigned short f2bf(float f) {
    union { float f; unsigned int i; } v; v.f = f;
    unsigned int x = v.i;
    return (unsigned short)((x + 0x7fffu + ((x >> 16) & 1u)) >> 16);
}

// ---------------- Kernel A: objects = scene @ W_feat + b_feat ----------------
__global__ __launch_bounds__(256) void gemm_objects(
        const float* __restrict__ scene, const float* __restrict__ W,
        const float* __restrict__ bias, float* __restrict__ obj) {
    __shared__ float sA[64][68];   // sA[k][o]
    __shared__ float sB[64][68];   // sB[k][d]
    const int b  = blockIdx.y;
    const int mt = (blockIdx.x >> 1) * 64;
    const int nt = (blockIdx.x & 1) * 64;
    const int tid = threadIdx.x;
    const int tx = tid & 15, ty = tid >> 4;
    float acc[4][4] = {{0.f,0.f,0.f,0.f},{0.f,0.f,0.f,0.f},{0.f,0.f,0.f,0.f},{0.f,0.f,0.f,0.f}};
    const float* sc = scene + (size_t)b * NOBJ * FDIM;
    for (int k0 = 0; k0 < FDIM; k0 += 64) {
        {
            const int o  = tid >> 2;
            const int ks = (tid & 3) * 16;
            const float4* src = (const float4*)(sc + (size_t)(mt + o) * FDIM + k0 + ks);
            #pragma unroll
            for (int j4 = 0; j4 < 4; j4++) {
                float4 v = src[j4];
                sA[ks + j4*4 + 0][o] = v.x;
                sA[ks + j4*4 + 1][o] = v.y;
                sA[ks + j4*4 + 2][o] = v.z;
                sA[ks + j4*4 + 3][o] = v.w;
            }
        }
        {
            const int kk = tid >> 2;
            const int dq = (tid & 3) * 16;
            const float4* src = (const float4*)(W + (size_t)(k0 + kk) * DD + nt + dq);
            float4* dst = (float4*)&sB[kk][dq];
            #pragma unroll
            for (int j4 = 0; j4 < 4; j4++) dst[j4] = src[j4];
        }
        __syncthreads();
        #pragma unroll 8
        for (int kk = 0; kk < 64; kk++) {
            float4 a4 = *(const float4*)&sA[kk][ty * 4];
            float4 b4 = *(const float4*)&sB[kk][tx * 4];
            float av[4] = {a4.x, a4.y, a4.z, a4.w};
            float bv[4] = {b4.x, b4.y, b4.z, b4.w};
            #pragma unroll
            for (int i = 0; i < 4; i++)
                #pragma unroll
                for (int j = 0; j < 4; j++)
                    acc[i][j] = fmaf(av[i], bv[j], acc[i][j]);
        }
        __syncthreads();
    }
    #pragma unroll
    for (int i = 0; i < 4; i++) {
        const int o = mt + ty * 4 + i;
        float4 r;
        r.x = acc[i][0] + bias[nt + tx*4 + 0];
        r.y = acc[i][1] + bias[nt + tx*4 + 1];
        r.z = acc[i][2] + bias[nt + tx*4 + 2];
        r.w = acc[i][3] + bias[nt + tx*4 + 3];
        *(float4*)(obj + ((size_t)b * NOBJ + o) * DD + nt + tx*4) = r;
    }
}

// -------- Kernel B: row L2 norms + bf16 copies (concepts + objects) ---------
__global__ __launch_bounds__(256) void norms_prep(
        const float* __restrict__ ct, const float* __restrict__ obj,
        float* __restrict__ cnorm, float* __restrict__ onorm,
        ushort_t* __restrict__ ctb, ushort_t* __restrict__ objb) {
    const int wid = threadIdx.x >> 6, lane = threadIdx.x & 63;
    const int r = blockIdx.x * 4 + wid;
    const int NROWS = MC + BB * NOBJ;
    if (r >= NROWS) return;
    const float* row = (r < MC) ? (ct + (size_t)r * DD) : (obj + (size_t)(r - MC) * DD);
    ushort_t* brow   = (r < MC) ? (ctb + (size_t)r * DD) : (objb + (size_t)(r - MC) * DD);
    float2 xy = *(const float2*)(row + lane * 2);
    float ss = xy.x * xy.x + xy.y * xy.y;
    ushort2 bv; bv.x = f2bf(xy.x); bv.y = f2bf(xy.y);
    *(ushort2*)(brow + lane * 2) = bv;
    #pragma unroll
    for (int off = 32; off; off >>= 1) ss += __shfl_xor(ss, off, 64);
    if (lane == 0) {
        if (r < MC) cnorm[r] = sqrtf(ss);
        else        onorm[r - MC] = sqrtf(ss);
    }
}

// -------- Kernel C: precomputed verify sigmoid tables for args 0..7 ----------
// sigc[a][n] for concept nodes (shared across samples); sigo[b][a][o] for objects.
__global__ __launch_bounds__(256) void sig_table(
        const float* __restrict__ ct, const float* __restrict__ obj,
        const float* __restrict__ cnorm, const float* __restrict__ onorm,
        float* __restrict__ sigc, float* __restrict__ sigo) {
    __shared__ float cv[NARG][DD];
    __shared__ float cn[NARG];
    const int tid = threadIdx.x;
    for (int a = 0; a < NARG; a++)
        for (int i = tid; i < DD; i += 256) cv[a][i] = ct[(size_t)a * DD + i];
    if (tid < NARG) cn[tid] = fmaxf(cnorm[tid], EPSC);
    __syncthreads();
    const int sub = tid & 7, slot = tid >> 3;   // 8 lanes/row, 32 rows/pass
    #pragma unroll
    for (int p = 0; p < 8; p++) {
        const int r = blockIdx.x * 256 + p * 32 + slot;
        const float* row = (r < MC) ? (ct + (size_t)r * DD) : (obj + (size_t)(r - MC) * DD);
        float4 r0 = *(const float4*)(row + sub * 16 + 0);
        float4 r1 = *(const float4*)(row + sub * 16 + 4);
        float4 r2 = *(const float4*)(row + sub * 16 + 8);
        float4 r3 = *(const float4*)(row + sub * 16 + 12);
        float rn = fmaxf((r < MC) ? cnorm[r] : onorm[r - MC], EPSC);
        for (int a = 0; a < NARG; a++) {
            const float* c = &cv[a][sub * 16];
            float dp = 0.f;
            dp = fmaf(r0.x, c[0], dp);  dp = fmaf(r0.y, c[1], dp);
            dp = fmaf(r0.z, c[2], dp);  dp = fmaf(r0.w, c[3], dp);
            dp = fmaf(r1.x, c[4], dp);  dp = fmaf(r1.y, c[5], dp);
            dp = fmaf(r1.z, c[6], dp);  dp = fmaf(r1.w, c[7], dp);
            dp = fmaf(r2.x, c[8], dp);  dp = fmaf(r2.y, c[9], dp);
            dp = fmaf(r2.z, c[10], dp); dp = fmaf(r2.w, c[11], dp);
            dp = fmaf(r3.x, c[12], dp); dp = fmaf(r3.y, c[13], dp);
            dp = fmaf(r3.z, c[14], dp); dp = fmaf(r3.w, c[15], dp);
            dp += __shfl_xor(dp, 1, 64);
            dp += __shfl_xor(dp, 2, 64);
            dp += __shfl_xor(dp, 4, 64);
            if (sub == 0) {
                float sim = dp / (rn * cn[a]);
                float g = 1.f / (1.f + __expf(-(sim - THC) * TEMPC));
                if (r < MC) sigc[(size_t)a * MC + r] = g;
                else {
                    int ro = r - MC, bb = ro >> 7, oo = ro & 127;
                    sigo[((size_t)bb * NARG + a) * NOBJ + oo] = g;
                }
            }
        }
    }
}

// ---------------- helpers ----------------
__device__ __forceinline__ float block_reduce_max(float v, float* red, int lane, int wid) {
    #pragma unroll
    for (int off = 32; off; off >>= 1) v = fmaxf(v, __shfl_xor(v, off, 64));
    if (lane == 0) red[wid] = v;
    __syncthreads();
    float r = red[0];
    #pragma unroll
    for (int w = 1; w < 16; w++) r = fmaxf(r, red[w]);
    __syncthreads();
    return r;
}
__device__ __forceinline__ float block_reduce_sum(float v, float* red, int lane, int wid) {
    #pragma unroll
    for (int off = 32; off; off >>= 1) v += __shfl_xor(v, off, 64);
    if (lane == 0) red[wid] = v;
    __syncthreads();
    float r = red[0];
    #pragma unroll
    for (int w = 1; w < 16; w++) r += red[w];
    __syncthreads();
    return r;
}

// f32 fallback sim pass (only used if a verify arg >= NARG ever appears)
__device__ __forceinline__ void sim_pass_f32(
        const float* __restrict__ ct, const float* __restrict__ myobj,
        const float* vec, const float* nrm, float* att,
        float vn, int tid) {
    const int sub = tid & 7, slot = tid >> 3;
    for (int n = slot; n < NN; n += 128) {
        const float* row = (n < MC) ? (ct + (size_t)n * DD)
                                    : (myobj + (size_t)(n - MC) * DD);
        float dp = 0.f;
        #pragma unroll
        for (int i = 0; i < 4; i++) {
            const float4 rv = *(const float4*)(row + sub * 16 + i * 4);
            const float4 vv = *(const float4*)(vec + sub * 16 + i * 4);
            dp = fmaf(rv.x, vv.x, dp); dp = fmaf(rv.y, vv.y, dp);
            dp = fmaf(rv.z, vv.z, dp); dp = fmaf(rv.w, vv.w, dp);
        }
        dp += __shfl_xor(dp, 1, 64);
        dp += __shfl_xor(dp, 2, 64);
        dp += __shfl_xor(dp, 4, 64);
        if (sub == 0) {
            float sim = dp / (fmaxf(nrm[n], EPSC) * vn);
            float g = 1.f / (1.f + __expf(-(sim - THC) * TEMPC));
            att[n] = fminf(att[n], g);
        }
    }
}

// ---------------- Kernel D: per-sample program scan ----------------
__global__ __launch_bounds__(1024) void scan_exec(
        const float* __restrict__ ct, const float* __restrict__ rt,
        const int* __restrict__ program, const float* __restrict__ obj,
        const float* __restrict__ cnorm, const float* __restrict__ onorm,
        const float* __restrict__ sigc, const float* __restrict__ sigo,
        const ushort_t* __restrict__ ctb, const ushort_t* __restrict__ objb,
        float* __restrict__ out, float* __restrict__ hist) {
    const int b    = blockIdx.x;
    const int tid  = threadIdx.x;
    const int lane = tid & 63, wid = tid >> 6;
    __shared__ __align__(16) float att[NN];
    __shared__ __align__(16) float nrm[NN];
    __shared__ __align__(16) float vec[DD];        // cvec or trans
    __shared__ __align__(16) float gv[DD];         // gather
    __shared__ __align__(16) float part[64 * DD];  // reduction partials (32 KB)
    __shared__ float red[16];
    const float*    myobj  = obj  + (size_t)b * NOBJ * DD;
    const ushort_t* myobjb = objb + (size_t)b * NOBJ * DD;

    for (int i = tid; i < NN; i += T) {
        att[i] = 1.0f;
        nrm[i] = (i < MC) ? cnorm[i] : onorm[b * NOBJ + (i - MC)];
    }
    __syncthreads();

    for (int step = 0; step < LL; step++) {
        const int op  = program[(b * LL + step) * 2 + 0];
        const int arg = program[(b * LL + step) * 2 + 1];

        if (op == 1) {                 // sel_obj
            for (int i = tid; i < MC; i += T) att[i] = 0.0f;
        } else if (op == 2) {          // sel_con
            for (int i = MC + tid; i < NN; i += T) att[i] = 0.0f;
        } else if (op == 3) {          // verify: table lookup
            if (arg < NARG) {
                const float* sc = sigc + (size_t)arg * MC;
                const float* so = sigo + ((size_t)b * NARG + arg) * NOBJ;
                for (int i = tid; i < NN; i += T) {
                    float g = (i < MC) ? sc[i] : so[i - MC];
                    att[i] = fminf(att[i], g);
                }
            } else {                   // robustness fallback (never hit for this data)
                if (tid < DD) vec[tid] = ct[(size_t)arg * DD + tid];
                __syncthreads();
                sim_pass_f32(ct, myobj, vec, nrm, att, fmaxf(cnorm[arg], EPSC), tid);
            }
        } else if (op == 4) {          // choose
            for (int i = tid; i < MC; i += T) att[i] = (i == arg) ? 1.0f : 0.0f;
        } else if (op == 5) {          // exist
            float lm = NINF;
            for (int i = tid; i < NN; i += T) lm = fmaxf(lm, att[i]);
            float s = block_reduce_max(lm, red, lane, wid);
            float yes = s * POSC;
            float no  = POSC - yes;
            for (int i = tid; i < NN; i += T)
                att[i] = (i == 0) ? yes : ((i == 1) ? no : NEGC);
        } else if (op == 6) {          // transfer (bf16 node sweeps, f32 accum)
            float lm = NINF;
            for (int i = tid; i < NN; i += T) lm = fmaxf(lm, att[i]);
            float s = block_reduce_max(lm, red, lane, wid);
            // gather[d] = sum_n att[n] * node[n][d]   (64 n-groups x 16 d-octets)
            const int ngrp = tid >> 4;
            const int doct = (tid & 15) * 8;
            float ac[8] = {0.f,0.f,0.f,0.f,0.f,0.f,0.f,0.f};
            for (int n = ngrp; n < NN; n += 64) {
                float a = att[n];
                if (a != 0.f) {
                    const ushort_t* row = (n < MC) ? (ctb + (size_t)n * DD)
                                                   : (myobjb + (size_t)(n - MC) * DD);
                    uint4 u = *(const uint4*)(row + doct);
                    ac[0] = fmaf(a, bfu(u.x & 0xffffu), ac[0]);
                    ac[1] = fmaf(a, bfu(u.x >> 16),     ac[1]);
                    ac[2] = fmaf(a, bfu(u.y & 0xffffu), ac[2]);
                    ac[3] = fmaf(a, bfu(u.y >> 16),     ac[3]);
                    ac[4] = fmaf(a, bfu(u.z & 0xffffu), ac[4]);
                    ac[5] = fmaf(a, bfu(u.z >> 16),     ac[5]);
                    ac[6] = fmaf(a, bfu(u.w & 0xffffu), ac[6]);
                    ac[7] = fmaf(a, bfu(u.w >> 16),     ac[7]);
                }
            }
            *(float4*)&part[ngrp * DD + doct]     = make_float4(ac[0], ac[1], ac[2], ac[3]);
            *(float4*)&part[ngrp * DD + doct + 4] = make_float4(ac[4], ac[5], ac[6], ac[7]);
            __syncthreads();
            if (tid < DD) {
                float g = 0.f;
                #pragma unroll
                for (int gi = 0; gi < 64; gi++) g += part[gi * DD + tid];
                gv[tid] = g;
            }
            __syncthreads();
            // trans[d'] = sum_d gather[d] * rmat[d][d']
            const float* rm = rt + (size_t)arg * (DD * DD);
            const int grp = tid >> 5, dq = (tid & 31) * 4;
            float qx = 0.f, qy = 0.f, qz = 0.f, qw = 0.f;
            for (int d = grp; d < DD; d += 32) {
                float g = gv[d];
                const float4 r = *(const float4*)(rm + (size_t)d * DD + dq);
                qx = fmaf(g, r.x, qx); qy = fmaf(g, r.y, qy);
                qz = fmaf(g, r.z, qz); qw = fmaf(g, r.w, qw);
            }
            *(float4*)&part[grp * DD + dq] = make_float4(qx, qy, qz, qw);
            __syncthreads();
            if (tid < DD) {
                float t = 0.f;
                #pragma unroll
                for (int gi = 0; gi < 32; gi++) t += part[gi * DD + tid];
                vec[tid] = t;
            }
            __syncthreads();
            if (wid == 0) {            // ||trans||
                float x = vec[lane], y = vec[lane + 64];
                float ss = x * x + y * y;
                #pragma unroll
                for (int off = 32; off; off >>= 1) ss += __shfl_xor(ss, off, 64);
                if (lane == 0) red[0] = sqrtf(ss);
            }
            __syncthreads();
            float tn = fmaxf(red[0], EPSC);
            // sim pass over bf16 nodes
            const int sub = tid & 7, slot = tid >> 3;
            for (int n = slot; n < NN; n += 128) {
                const ushort_t* row = (n < MC) ? (ctb + (size_t)n * DD)
                                               : (myobjb + (size_t)(n - MC) * DD);
                uint4 u0 = *(const uint4*)(row + sub * 16);
                uint4 u1 = *(const uint4*)(row + sub * 16 + 8);
                const float* v = &vec[sub * 16];
                float dp = 0.f;
                dp = fmaf(bfu(u0.x & 0xffffu), v[0], dp);
                dp = fmaf(bfu(u0.x >> 16),     v[1], dp);
                dp = fmaf(bfu(u0.y & 0xffffu), v[2], dp);
                dp = fmaf(bfu(u0.y >> 16),     v[3], dp);
                dp = fmaf(bfu(u0.z & 0xffffu), v[4], dp);
                dp = fmaf(bfu(u0.z >> 16),     v[5], dp);
                dp = fmaf(bfu(u0.w & 0xffffu), v[6], dp);
                dp = fmaf(bfu(u0.w >> 16),     v[7], dp);
                dp = fmaf(bfu(u1.x & 0xffffu), v[8], dp);
                dp = fmaf(bfu(u1.x >> 16),     v[9], dp);
                dp = fmaf(bfu(u1.y & 0xffffu), v[10], dp);
                dp = fmaf(bfu(u1.y >> 16),     v[11], dp);
                dp = fmaf(bfu(u1.z & 0xffffu), v[12], dp);
                dp = fmaf(bfu(u1.z >> 16),     v[13], dp);
                dp = fmaf(bfu(u1.w & 0xffffu), v[14], dp);
                dp = fmaf(bfu(u1.w >> 16),     v[15], dp);
                dp += __shfl_xor(dp, 1, 64);
                dp += __shfl_xor(dp, 2, 64);
                dp += __shfl_xor(dp, 4, 64);
                if (sub == 0) {
                    float sim = dp / (fmaxf(nrm[n], EPSC) * tn);
                    float g = 1.f / (1.f + __expf(-(sim - THC) * TEMPC));
                    att[n] = g * s;
                }
            }
        }
        // op == 0: null

        __syncthreads();
        float* hrow = hist + ((size_t)b * LL + step) * NN;
        for (int i = tid; i < NN; i += T) hrow[i] = att[i];
        __syncthreads();
    }

    // log_softmax over att[0:MC]
    float lm = NINF;
    for (int i = tid; i < MC; i += T) lm = fmaxf(lm, att[i]);
    float m = block_reduce_max(lm, red, lane, wid);
    float lse = 0.f;
    for (int i = tid; i < MC; i += T) lse += expf(att[i] - m);
    float se = block_reduce_sum(lse, red, lane, wid);
    float ls = logf(se);
    for (int i = tid; i < MC; i += T)
        out[(size_t)b * MC + i] = att[i] - m - ls;
}

extern "C" void kernel_launch(void* const* d_in, const int* in_sizes, int n_in,
                              void* d_out, int out_size, void* d_ws, size_t ws_size,
                              hipStream_t stream) {
    const float* scene = (const float*)d_in[0];
    const int*   prog  = (const int*)d_in[1];
    const float* ct    = (const float*)d_in[2];
    const float* rt    = (const float*)d_in[3];
    const float* W     = (const float*)d_in[4];
    const float* bias  = (const float*)d_in[5];

    float* out  = (float*)d_out;
    float* hist = out + (size_t)BB * MC;

    float* obj   = (float*)d_ws;                       // B*NOBJ*D
    float* cnorm = obj + (size_t)BB * NOBJ * DD;       // MC
    float* onorm = cnorm + MC;                         // B*NOBJ
    float* sigc  = onorm + (size_t)BB * NOBJ;          // NARG*MC
    float* sigo  = sigc + (size_t)NARG * MC;           // B*NARG*NOBJ
    ushort_t* ctb  = (ushort_t*)(sigo + (size_t)BB * NARG * NOBJ);  // MC*DD
    ushort_t* objb = ctb + (size_t)MC * DD;            // B*NOBJ*DD

    gemm_objects<<<dim3(4, BB), 256, 0, stream>>>(scene, W, bias, obj);
    norms_prep<<<dim3((MC + BB * NOBJ) / 4), 256, 0, stream>>>(ct, obj, cnorm, onorm, ctb, objb);
    sig_table<<<dim3((MC + BB * NOBJ) / 256), 256, 0, stream>>>(ct, obj, cnorm, onorm, sigc, sigo);
    scan_exec<<<dim3(BB), 1024, 0, stream>>>(ct, rt, prog, obj, cnorm, onorm,
                                             sigc, sigo, ctb, objb, out, hist);
}

// Round 3
// 338.079 us; speedup vs baseline: 1.1048x; 1.0009x over previous
//
#include <hip/hip_runtime.h>
#include <math.h>

#define MC   2048
#define DD   128
#define BB   64
#define LL   16
#define NOBJ 128
#define FDIM 512
#define NN   (MC + NOBJ)
#define TEMPC 3.0f
#define THC   0.8f
#define POSC  10.0f
#define NEGC  (-10.0f)
#define EPSC  1e-8f
#define T     1024
#define NARG 8
#define NINF  (-3.402823466e38f)
#define FSCALE 2048.0f
#define INV_FSCALE (1.0f/2048.0f)

typedef unsigned short ushort_t;
typedef float v2f __attribute__((ext_vector_type(2)));

// ---------- fp8 e4m3 (OCP) helpers ----------
#if defined(__has_builtin)
#if __has_builtin(__builtin_amdgcn_cvt_pk_f32_fp8)
#define HAS_HW_FP8 1
#endif
#endif

__device__ __forceinline__ float e4m3_dec1(unsigned int b) {
    unsigned int s = (b >> 7) & 1u, E = (b >> 3) & 15u, M = b & 7u;
    float v;
    if (E) v = __uint_as_float(((E + 120u) << 23) | (M << 20));
    else   v = (float)M * 0.001953125f;
    return s ? -v : v;
}
__device__ __forceinline__ v2f f8pair_sw(unsigned int w) {
    v2f r; r[0] = e4m3_dec1(w & 0xffu); r[1] = e4m3_dec1((w >> 8) & 0xffu); return r;
}
#ifdef HAS_HW_FP8
#define F8LO(u) __builtin_amdgcn_cvt_pk_f32_fp8((u), false)
#define F8HI(u) __builtin_amdgcn_cvt_pk_f32_fp8((u), true)
#else
#define F8LO(u) f8pair_sw((u) & 0xffffu)
#define F8HI(u) f8pair_sw((u) >> 16)
#endif

// software RNE encoder (prep only; controlled rounding, no builtin dependency)
__device__ __forceinline__ unsigned int f32_to_e4m3(float x) {
    float a = fabsf(x);
    unsigned int s = (__float_as_uint(x) >> 31) << 7;
    if (a == 0.0f) return s;
    if (a >= 448.0f) return s | 0x7Eu;
    int e; float m = frexpf(a, &e);            // a = m * 2^e, m in [0.5,1)
    if (e >= -5) {                             // normal: 1.mmm * 2^(e-1)
        int mant = (int)rintf(m * 16.0f);      // 8..16
        if (mant == 16) { mant = 8; e++; if (e - 1 > 8) return s | 0x7Eu; }
        return s | ((unsigned)(e - 1 + 7) << 3) | (unsigned)(mant - 8);
    } else {                                   // subnormal: M * 2^-9
        int q = (int)rintf(a * 512.0f);
        if (q >= 8) return s | 0x08u;
        return s | (unsigned)q;
    }
}

// ---------------- Kernel A: objects = scene @ W_feat + b_feat ----------------
__global__ __launch_bounds__(256) void gemm_objects(
        const float* __restrict__ scene, const float* __restrict__ W,
        const float* __restrict__ bias, float* __restrict__ obj) {
    __shared__ float sA[64][68];   // sA[k][o]
    __shared__ float sB[64][68];   // sB[k][d]
    const int b  = blockIdx.y;
    const int mt = (blockIdx.x >> 1) * 64;
    const int nt = (blockIdx.x & 1) * 64;
    const int tid = threadIdx.x;
    const int tx = tid & 15, ty = tid >> 4;
    float acc[4][4] = {{0.f,0.f,0.f,0.f},{0.f,0.f,0.f,0.f},{0.f,0.f,0.f,0.f},{0.f,0.f,0.f,0.f}};
    const float* sc = scene + (size_t)b * NOBJ * FDIM;
    for (int k0 = 0; k0 < FDIM; k0 += 64) {
        {
            const int o  = tid >> 2;
            const int ks = (tid & 3) * 16;
            const float4* src = (const float4*)(sc + (size_t)(mt + o) * FDIM + k0 + ks);
            #pragma unroll
            for (int j4 = 0; j4 < 4; j4++) {
                float4 v = src[j4];
                sA[ks + j4*4 + 0][o] = v.x;
                sA[ks + j4*4 + 1][o] = v.y;
                sA[ks + j4*4 + 2][o] = v.z;
                sA[ks + j4*4 + 3][o] = v.w;
            }
        }
        {
            const int kk = tid >> 2;
            const int dq = (tid & 3) * 16;
            const float4* src = (const float4*)(W + (size_t)(k0 + kk) * DD + nt + dq);
            float4* dst = (float4*)&sB[kk][dq];
            #pragma unroll
            for (int j4 = 0; j4 < 4; j4++) dst[j4] = src[j4];
        }
        __syncthreads();
        #pragma unroll 8
        for (int kk = 0; kk < 64; kk++) {
            float4 a4 = *(const float4*)&sA[kk][ty * 4];
            float4 b4 = *(const float4*)&sB[kk][tx * 4];
            float av[4] = {a4.x, a4.y, a4.z, a4.w};
            float bv[4] = {b4.x, b4.y, b4.z, b4.w};
            #pragma unroll
            for (int i = 0; i < 4; i++)
                #pragma unroll
                for (int j = 0; j < 4; j++)
                    acc[i][j] = fmaf(av[i], bv[j], acc[i][j]);
        }
        __syncthreads();
    }
    #pragma unroll
    for (int i = 0; i < 4; i++) {
        const int o = mt + ty * 4 + i;
        float4 r;
        r.x = acc[i][0] + bias[nt + tx*4 + 0];
        r.y = acc[i][1] + bias[nt + tx*4 + 1];
        r.z = acc[i][2] + bias[nt + tx*4 + 2];
        r.w = acc[i][3] + bias[nt + tx*4 + 3];
        *(float4*)(obj + ((size_t)b * NOBJ + o) * DD + nt + tx*4) = r;
    }
}

// -------- Kernel B: row L2 norms + fp8 copies (scaled by FSCALE) ------------
__global__ __launch_bounds__(256) void norms_prep(
        const float* __restrict__ ct, const float* __restrict__ obj,
        float* __restrict__ cnorm, float* __restrict__ onorm,
        unsigned char* __restrict__ ctf8, unsigned char* __restrict__ objf8) {
    const int wid = threadIdx.x >> 6, lane = threadIdx.x & 63;
    const int r = blockIdx.x * 4 + wid;
    const int NROWS = MC + BB * NOBJ;
    if (r >= NROWS) return;
    const float* row = (r < MC) ? (ct + (size_t)r * DD) : (obj + (size_t)(r - MC) * DD);
    unsigned char* brow = (r < MC) ? (ctf8 + (size_t)r * DD) : (objf8 + (size_t)(r - MC) * DD);
    float2 xy = *(const float2*)(row + lane * 2);
    float ss = xy.x * xy.x + xy.y * xy.y;
    unsigned int b0 = f32_to_e4m3(xy.x * FSCALE);
    unsigned int b1 = f32_to_e4m3(xy.y * FSCALE);
    *(ushort_t*)(brow + lane * 2) = (ushort_t)(b0 | (b1 << 8));
    #pragma unroll
    for (int off = 32; off; off >>= 1) ss += __shfl_xor(ss, off, 64);
    if (lane == 0) {
        if (r < MC) cnorm[r] = sqrtf(ss);
        else        onorm[r - MC] = sqrtf(ss);
    }
}

// -------- Kernel C: precomputed verify sigmoid tables for args 0..7 ----------
__global__ __launch_bounds__(256) void sig_table(
        const float* __restrict__ ct, const float* __restrict__ obj,
        const float* __restrict__ cnorm, const float* __restrict__ onorm,
        float* __restrict__ sigc, float* __restrict__ sigo) {
    __shared__ float cv[NARG][DD];
    __shared__ float cn[NARG];
    const int tid = threadIdx.x;
    for (int a = 0; a < NARG; a++)
        for (int i = tid; i < DD; i += 256) cv[a][i] = ct[(size_t)a * DD + i];
    if (tid < NARG) cn[tid] = fmaxf(cnorm[tid], EPSC);
    __syncthreads();
    const int sub = tid & 7, slot = tid >> 3;
    #pragma unroll
    for (int p = 0; p < 8; p++) {
        const int r = blockIdx.x * 256 + p * 32 + slot;
        const float* row = (r < MC) ? (ct + (size_t)r * DD) : (obj + (size_t)(r - MC) * DD);
        float4 r0 = *(const float4*)(row + sub * 16 + 0);
        float4 r1 = *(const float4*)(row + sub * 16 + 4);
        float4 r2 = *(const float4*)(row + sub * 16 + 8);
        float4 r3 = *(const float4*)(row + sub * 16 + 12);
        float rn = fmaxf((r < MC) ? cnorm[r] : onorm[r - MC], EPSC);
        for (int a = 0; a < NARG; a++) {
            const float* c = &cv[a][sub * 16];
            float dp = 0.f;
            dp = fmaf(r0.x, c[0], dp);  dp = fmaf(r0.y, c[1], dp);
            dp = fmaf(r0.z, c[2], dp);  dp = fmaf(r0.w, c[3], dp);
            dp = fmaf(r1.x, c[4], dp);  dp = fmaf(r1.y, c[5], dp);
            dp = fmaf(r1.z, c[6], dp);  dp = fmaf(r1.w, c[7], dp);
            dp = fmaf(r2.x, c[8], dp);  dp = fmaf(r2.y, c[9], dp);
            dp = fmaf(r2.z, c[10], dp); dp = fmaf(r2.w, c[11], dp);
            dp = fmaf(r3.x, c[12], dp); dp = fmaf(r3.y, c[13], dp);
            dp = fmaf(r3.z, c[14], dp); dp = fmaf(r3.w, c[15], dp);
            dp += __shfl_xor(dp, 1, 64);
            dp += __shfl_xor(dp, 2, 64);
            dp += __shfl_xor(dp, 4, 64);
            if (sub == 0) {
                float sim = dp / (rn * cn[a]);
                float g = 1.f / (1.f + __expf(-(sim - THC) * TEMPC));
                if (r < MC) sigc[(size_t)a * MC + r] = g;
                else {
                    int ro = r - MC, bb = ro >> 7, oo = ro & 127;
                    sigo[((size_t)bb * NARG + a) * NOBJ + oo] = g;
                }
            }
        }
    }
}

// ---------------- helpers ----------------
__device__ __forceinline__ float block_reduce_max(float v, float* red, int lane, int wid) {
    #pragma unroll
    for (int off = 32; off; off >>= 1) v = fmaxf(v, __shfl_xor(v, off, 64));
    if (lane == 0) red[wid] = v;
    __syncthreads();
    float r = red[0];
    #pragma unroll
    for (int w = 1; w < 16; w++) r = fmaxf(r, red[w]);
    __syncthreads();
    return r;
}
__device__ __forceinline__ float block_reduce_sum(float v, float* red, int lane, int wid) {
    #pragma unroll
    for (int off = 32; off; off >>= 1) v += __shfl_xor(v, off, 64);
    if (lane == 0) red[wid] = v;
    __syncthreads();
    float r = red[0];
    #pragma unroll
    for (int w = 1; w < 16; w++) r += red[w];
    __syncthreads();
    return r;
}

// f32 fallback sim pass (only used if a verify arg >= NARG ever appears).
// nrm[] holds FSCALE-scaled norms -> rescale.
__device__ __forceinline__ void sim_pass_f32(
        const float* __restrict__ ct, const float* __restrict__ myobj,
        const float* vec, const float* nrm, float* att,
        float vn, int tid) {
    const int sub = tid & 7, slot = tid >> 3;
    for (int n = slot; n < NN; n += 128) {
        const float* row = (n < MC) ? (ct + (size_t)n * DD)
                                    : (myobj + (size_t)(n - MC) * DD);
        float dp = 0.f;
        #pragma unroll
        for (int i = 0; i < 4; i++) {
            const float4 rv = *(const float4*)(row + sub * 16 + i * 4);
            const float4 vv = *(const float4*)(vec + sub * 16 + i * 4);
            dp = fmaf(rv.x, vv.x, dp); dp = fmaf(rv.y, vv.y, dp);
            dp = fmaf(rv.z, vv.z, dp); dp = fmaf(rv.w, vv.w, dp);
        }
        dp += __shfl_xor(dp, 1, 64);
        dp += __shfl_xor(dp, 2, 64);
        dp += __shfl_xor(dp, 4, 64);
        if (sub == 0) {
            float sim = dp / (fmaxf(nrm[n] * INV_FSCALE, EPSC) * vn);
            float g = 1.f / (1.f + __expf(-(sim - THC) * TEMPC));
            att[n] = fminf(att[n], g);
        }
    }
}

// ---------------- Kernel D: per-sample program scan ----------------
__global__ __launch_bounds__(1024) void scan_exec(
        const float* __restrict__ ct, const float* __restrict__ rt,
        const int* __restrict__ program, const float* __restrict__ obj,
        const float* __restrict__ cnorm, const float* __restrict__ onorm,
        const float* __restrict__ sigc, const float* __restrict__ sigo,
        const unsigned char* __restrict__ ctf8, const unsigned char* __restrict__ objf8,
        float* __restrict__ out, float* __restrict__ hist) {
    const int b    = blockIdx.x;
    const int tid  = threadIdx.x;
    const int lane = tid & 63, wid = tid >> 6;
    __shared__ __align__(16) float att[NN];
    __shared__ __align__(16) float nrm[NN];       // FSCALE-scaled norms
    __shared__ __align__(16) float vec[DD];       // scaled trans
    __shared__ __align__(16) float gv[DD];        // scaled gather
    __shared__ __align__(16) float part[64 * DD]; // reduction partials (32 KB)
    __shared__ float red[16];
    const float*         myobj   = obj   + (size_t)b * NOBJ * DD;
    const unsigned char* myobjf8 = objf8 + (size_t)b * NOBJ * DD;

    for (int i = tid; i < NN; i += T) {
        att[i] = 1.0f;
        nrm[i] = FSCALE * ((i < MC) ? cnorm[i] : onorm[b * NOBJ + (i - MC)]);
    }
    __syncthreads();

    for (int step = 0; step < LL; step++) {
        const int op  = program[(b * LL + step) * 2 + 0];
        const int arg = program[(b * LL + step) * 2 + 1];

        if (op == 1) {                 // sel_obj
            for (int i = tid; i < MC; i += T) att[i] = 0.0f;
        } else if (op == 2) {          // sel_con
            for (int i = MC + tid; i < NN; i += T) att[i] = 0.0f;
        } else if (op == 3) {          // verify: table lookup
            if (arg < NARG) {
                const float* sc = sigc + (size_t)arg * MC;
                const float* so = sigo + ((size_t)b * NARG + arg) * NOBJ;
                for (int i = tid; i < NN; i += T) {
                    float g = (i < MC) ? sc[i] : so[i - MC];
                    att[i] = fminf(att[i], g);
                }
            } else {                   // robustness fallback (never hit for this data)
                if (tid < DD) vec[tid] = ct[(size_t)arg * DD + tid];
                __syncthreads();
                sim_pass_f32(ct, myobj, vec, nrm, att, fmaxf(cnorm[arg], EPSC), tid);
            }
        } else if (op == 4) {          // choose
            for (int i = tid; i < MC; i += T) att[i] = (i == arg) ? 1.0f : 0.0f;
        } else if (op == 5) {          // exist
            float lm = NINF;
            for (int i = tid; i < NN; i += T) lm = fmaxf(lm, att[i]);
            float s = block_reduce_max(lm, red, lane, wid);
            float yes = s * POSC;
            float no  = POSC - yes;
            for (int i = tid; i < NN; i += T)
                att[i] = (i == 0) ? yes : ((i == 1) ? no : NEGC);
        } else if (op == 6) {          // transfer (fp8 node sweeps, f32 accum)
            float lm = NINF;
            for (int i = tid; i < NN; i += T) lm = fmaxf(lm, att[i]);
            float s = block_reduce_max(lm, red, lane, wid);
            // gather[d] = sum_n att[n] * node_s[n][d]   (64 n-groups x 16 d-octets)
            const int ngrp = tid >> 4;
            const int doct = (tid & 15) * 8;
            float ac[8] = {0.f,0.f,0.f,0.f,0.f,0.f,0.f,0.f};
            for (int n = ngrp; n < NN; n += 64) {
                float a = att[n];
                if (a != 0.f) {
                    const unsigned char* row = (n < MC) ? (ctf8 + (size_t)n * DD)
                                                        : (myobjf8 + (size_t)(n - MC) * DD);
                    uint2 u = *(const uint2*)(row + doct);
                    v2f g0 = F8LO(u.x), g1 = F8HI(u.x), g2 = F8LO(u.y), g3 = F8HI(u.y);
                    ac[0] = fmaf(a, g0[0], ac[0]);
                    ac[1] = fmaf(a, g0[1], ac[1]);
                    ac[2] = fmaf(a, g1[0], ac[2]);
                    ac[3] = fmaf(a, g1[1], ac[3]);
                    ac[4] = fmaf(a, g2[0], ac[4]);
                    ac[5] = fmaf(a, g2[1], ac[5]);
                    ac[6] = fmaf(a, g3[0], ac[6]);
                    ac[7] = fmaf(a, g3[1], ac[7]);
                }
            }
            *(float4*)&part[ngrp * DD + doct]     = make_float4(ac[0], ac[1], ac[2], ac[3]);
            *(float4*)&part[ngrp * DD + doct + 4] = make_float4(ac[4], ac[5], ac[6], ac[7]);
            __syncthreads();
            if (tid < DD) {
                float g = 0.f;
                #pragma unroll
                for (int gi = 0; gi < 64; gi++) g += part[gi * DD + tid];
                gv[tid] = g;
            }
            __syncthreads();
            // trans[d'] = sum_d gather[d] * rmat[d][d']  (f32 rmat)
            const float* rm = rt + (size_t)arg * (DD * DD);
            const int grp = tid >> 5, dq = (tid & 31) * 4;
            float qx = 0.f, qy = 0.f, qz = 0.f, qw = 0.f;
            for (int d = grp; d < DD; d += 32) {
                float g = gv[d];
                const float4 r = *(const float4*)(rm + (size_t)d * DD + dq);
                qx = fmaf(g, r.x, qx); qy = fmaf(g, r.y, qy);
                qz = fmaf(g, r.z, qz); qw = fmaf(g, r.w, qw);
            }
            *(float4*)&part[grp * DD + dq] = make_float4(qx, qy, qz, qw);
            __syncthreads();
            if (tid < DD) {
                float t = 0.f;
                #pragma unroll
                for (int gi = 0; gi < 32; gi++) t += part[gi * DD + tid];
                vec[tid] = t;
            }
            __syncthreads();
            if (wid == 0) {            // ||trans|| (scaled)
                float x = vec[lane], y = vec[lane + 64];
                float ss = x * x + y * y;
                #pragma unroll
                for (int off = 32; off; off >>= 1) ss += __shfl_xor(ss, off, 64);
                if (lane == 0) red[0] = sqrtf(ss);
            }
            __syncthreads();
            float tn = fmaxf(red[0], EPSC);
            // sim pass over fp8 nodes (scaled): 8 lanes/row, 16 fp8 each (uint4)
            const int sub = tid & 7, slot = tid >> 3;
            #pragma unroll 4
            for (int n = slot; n < NN; n += 128) {
                const unsigned char* row = (n < MC) ? (ctf8 + (size_t)n * DD)
                                                    : (myobjf8 + (size_t)(n - MC) * DD);
                uint4 u = *(const uint4*)(row + sub * 16);
                v2f a0 = F8LO(u.x), a1 = F8HI(u.x), a2 = F8LO(u.y), a3 = F8HI(u.y);
                v2f a4 = F8LO(u.z), a5 = F8HI(u.z), a6 = F8LO(u.w), a7 = F8HI(u.w);
                const float* v = &vec[sub * 16];
                float dp = 0.f;
                dp = fmaf(a0[0], v[0],  dp); dp = fmaf(a0[1], v[1],  dp);
                dp = fmaf(a1[0], v[2],  dp); dp = fmaf(a1[1], v[3],  dp);
                dp = fmaf(a2[0], v[4],  dp); dp = fmaf(a2[1], v[5],  dp);
                dp = fmaf(a3[0], v[6],  dp); dp = fmaf(a3[1], v[7],  dp);
                dp = fmaf(a4[0], v[8],  dp); dp = fmaf(a4[1], v[9],  dp);
                dp = fmaf(a5[0], v[10], dp); dp = fmaf(a5[1], v[11], dp);
                dp = fmaf(a6[0], v[12], dp); dp = fmaf(a6[1], v[13], dp);
                dp = fmaf(a7[0], v[14], dp); dp = fmaf(a7[1], v[15], dp);
                dp += __shfl_xor(dp, 1, 64);
                dp += __shfl_xor(dp, 2, 64);
                dp += __shfl_xor(dp, 4, 64);
                if (sub == 0) {
                    float sim = dp / (nrm[n] * tn);
                    float g = 1.f / (1.f + __expf(-(sim - THC) * TEMPC));
                    att[n] = g * s;
                }
            }
        }
        // op == 0: null

        __syncthreads();
        float* hrow = hist + ((size_t)b * LL + step) * NN;
        for (int i = tid; i < NN; i += T) hrow[i] = att[i];
        __syncthreads();
    }

    // log_softmax over att[0:MC]
    float lm = NINF;
    for (int i = tid; i < MC; i += T) lm = fmaxf(lm, att[i]);
    float m = block_reduce_max(lm, red, lane, wid);
    float lse = 0.f;
    for (int i = tid; i < MC; i += T) lse += expf(att[i] - m);
    float se = block_reduce_sum(lse, red, lane, wid);
    float ls = logf(se);
    for (int i = tid; i < MC; i += T)
        out[(size_t)b * MC + i] = att[i] - m - ls;
}

extern "C" void kernel_launch(void* const* d_in, const int* in_sizes, int n_in,
                              void* d_out, int out_size, void* d_ws, size_t ws_size,
                              hipStream_t stream) {
    const float* scene = (const float*)d_in[0];
    const int*   prog  = (const int*)d_in[1];
    const float* ct    = (const float*)d_in[2];
    const float* rt    = (const float*)d_in[3];
    const float* W     = (const float*)d_in[4];
    const float* bias  = (const float*)d_in[5];

    float* out  = (float*)d_out;
    float* hist = out + (size_t)BB * MC;

    float* obj   = (float*)d_ws;                       // B*NOBJ*D f32
    float* cnorm = obj + (size_t)BB * NOBJ * DD;       // MC
    float* onorm = cnorm + MC;                         // B*NOBJ
    float* sigc  = onorm + (size_t)BB * NOBJ;          // NARG*MC
    float* sigo  = sigc + (size_t)NARG * MC;           // B*NARG*NOBJ
    unsigned char* ctf8  = (unsigned char*)(sigo + (size_t)BB * NARG * NOBJ);  // MC*DD bytes
    unsigned char* objf8 = ctf8 + (size_t)MC * DD;     // B*NOBJ*DD bytes

    gemm_objects<<<dim3(4, BB), 256, 0, stream>>>(scene, W, bias, obj);
    norms_prep<<<dim3((MC + BB * NOBJ) / 4), 256, 0, stream>>>(ct, obj, cnorm, onorm, ctf8, objf8);
    sig_table<<<dim3((MC + BB * NOBJ) / 256), 256, 0, stream>>>(ct, obj, cnorm, onorm, sigc, sigo);
    scan_exec<<<dim3(BB), 1024, 0, stream>>>(ct, rt, prog, obj, cnorm, onorm,
                                             sigc, sigo, ctf8, objf8, out, hist);
}

// Round 4
// 332.245 us; speedup vs baseline: 1.1242x; 1.0176x over previous
//
#include <hip/hip_runtime.h>
#include <math.h>

#define MC   2048
#define DD   128
#define BB   64
#define LL   16
#define NOBJ 128
#define FDIM 512
#define NN   (MC + NOBJ)
#define TEMPC 3.0f
#define THC   0.8f
#define POSC  10.0f
#define NEGC  (-10.0f)
#define EPSC  1e-8f
#define T     1024
#define NARG 8
#define NINF  (-3.402823466e38f)
#define FSCALE 2048.0f
#define INV_FSCALE (1.0f/2048.0f)

typedef unsigned short ushort_t;
typedef float v2f __attribute__((ext_vector_type(2)));

// ---------- fp8 e4m3 (OCP) helpers ----------
#if defined(__has_builtin)
#if __has_builtin(__builtin_amdgcn_cvt_pk_f32_fp8)
#define HAS_HW_FP8 1
#endif
#endif

__device__ __forceinline__ float e4m3_dec1(unsigned int b) {
    unsigned int s = (b >> 7) & 1u, E = (b >> 3) & 15u, M = b & 7u;
    float v;
    if (E) v = __uint_as_float(((E + 120u) << 23) | (M << 20));
    else   v = (float)M * 0.001953125f;
    return s ? -v : v;
}
__device__ __forceinline__ v2f f8pair_sw(unsigned int w) {
    v2f r; r[0] = e4m3_dec1(w & 0xffu); r[1] = e4m3_dec1((w >> 8) & 0xffu); return r;
}
#ifdef HAS_HW_FP8
#define F8LO(u) __builtin_amdgcn_cvt_pk_f32_fp8((u), false)
#define F8HI(u) __builtin_amdgcn_cvt_pk_f32_fp8((u), true)
#else
#define F8LO(u) f8pair_sw((u) & 0xffffu)
#define F8HI(u) f8pair_sw((u) >> 16)
#endif

// software RNE encoder (prep only)
__device__ __forceinline__ unsigned int f32_to_e4m3(float x) {
    float a = fabsf(x);
    unsigned int s = (__float_as_uint(x) >> 31) << 7;
    if (a == 0.0f) return s;
    if (a >= 448.0f) return s | 0x7Eu;
    int e; float m = frexpf(a, &e);            // a = m * 2^e, m in [0.5,1)
    if (e >= -5) {                             // normal
        int mant = (int)rintf(m * 16.0f);      // 8..16
        if (mant == 16) { mant = 8; e++; if (e - 1 > 8) return s | 0x7Eu; }
        return s | ((unsigned)(e - 1 + 7) << 3) | (unsigned)(mant - 8);
    } else {                                   // subnormal: M * 2^-9
        int q = (int)rintf(a * 512.0f);
        if (q >= 8) return s | 0x08u;
        return s | (unsigned)q;
    }
}

// ---------------- Kernel A: objects = scene @ W_feat + b_feat ----------------
__global__ __launch_bounds__(256) void gemm_objects(
        const float* __restrict__ scene, const float* __restrict__ W,
        const float* __restrict__ bias, float* __restrict__ obj) {
    __shared__ float sA[64][68];   // sA[k][o]
    __shared__ float sB[64][68];   // sB[k][d]
    const int b  = blockIdx.y;
    const int mt = (blockIdx.x >> 1) * 64;
    const int nt = (blockIdx.x & 1) * 64;
    const int tid = threadIdx.x;
    const int tx = tid & 15, ty = tid >> 4;
    float acc[4][4] = {{0.f,0.f,0.f,0.f},{0.f,0.f,0.f,0.f},{0.f,0.f,0.f,0.f},{0.f,0.f,0.f,0.f}};
    const float* sc = scene + (size_t)b * NOBJ * FDIM;
    for (int k0 = 0; k0 < FDIM; k0 += 64) {
        {
            const int o  = tid >> 2;
            const int ks = (tid & 3) * 16;
            const float4* src = (const float4*)(sc + (size_t)(mt + o) * FDIM + k0 + ks);
            #pragma unroll
            for (int j4 = 0; j4 < 4; j4++) {
                float4 v = src[j4];
                sA[ks + j4*4 + 0][o] = v.x;
                sA[ks + j4*4 + 1][o] = v.y;
                sA[ks + j4*4 + 2][o] = v.z;
                sA[ks + j4*4 + 3][o] = v.w;
            }
        }
        {
            const int kk = tid >> 2;
            const int dq = (tid & 3) * 16;
            const float4* src = (const float4*)(W + (size_t)(k0 + kk) * DD + nt + dq);
            float4* dst = (float4*)&sB[kk][dq];
            #pragma unroll
            for (int j4 = 0; j4 < 4; j4++) dst[j4] = src[j4];
        }
        __syncthreads();
        #pragma unroll 8
        for (int kk = 0; kk < 64; kk++) {
            float4 a4 = *(const float4*)&sA[kk][ty * 4];
            float4 b4 = *(const float4*)&sB[kk][tx * 4];
            float av[4] = {a4.x, a4.y, a4.z, a4.w};
            float bv[4] = {b4.x, b4.y, b4.z, b4.w};
            #pragma unroll
            for (int i = 0; i < 4; i++)
                #pragma unroll
                for (int j = 0; j < 4; j++)
                    acc[i][j] = fmaf(av[i], bv[j], acc[i][j]);
        }
        __syncthreads();
    }
    #pragma unroll
    for (int i = 0; i < 4; i++) {
        const int o = mt + ty * 4 + i;
        float4 r;
        r.x = acc[i][0] + bias[nt + tx*4 + 0];
        r.y = acc[i][1] + bias[nt + tx*4 + 1];
        r.z = acc[i][2] + bias[nt + tx*4 + 2];
        r.w = acc[i][3] + bias[nt + tx*4 + 3];
        *(float4*)(obj + ((size_t)b * NOBJ + o) * DD + nt + tx*4) = r;
    }
}

// -------- Kernel B: row L2 norms + fp8 copies (scaled by FSCALE) ------------
__global__ __launch_bounds__(256) void norms_prep(
        const float* __restrict__ ct, const float* __restrict__ obj,
        float* __restrict__ cnorm, float* __restrict__ onorm,
        unsigned char* __restrict__ ctf8, unsigned char* __restrict__ objf8) {
    const int wid = threadIdx.x >> 6, lane = threadIdx.x & 63;
    const int r = blockIdx.x * 4 + wid;
    const int NROWS = MC + BB * NOBJ;
    if (r >= NROWS) return;
    const float* row = (r < MC) ? (ct + (size_t)r * DD) : (obj + (size_t)(r - MC) * DD);
    unsigned char* brow = (r < MC) ? (ctf8 + (size_t)r * DD) : (objf8 + (size_t)(r - MC) * DD);
    float2 xy = *(const float2*)(row + lane * 2);
    float ss = xy.x * xy.x + xy.y * xy.y;
    unsigned int b0 = f32_to_e4m3(xy.x * FSCALE);
    unsigned int b1 = f32_to_e4m3(xy.y * FSCALE);
    *(ushort_t*)(brow + lane * 2) = (ushort_t)(b0 | (b1 << 8));
    #pragma unroll
    for (int off = 32; off; off >>= 1) ss += __shfl_xor(ss, off, 64);
    if (lane == 0) {
        if (r < MC) cnorm[r] = sqrtf(ss);
        else        onorm[r - MC] = sqrtf(ss);
    }
}

// -------- Kernel C: precomputed verify sigmoid tables for args 0..7 ----------
__global__ __launch_bounds__(256) void sig_table(
        const float* __restrict__ ct, const float* __restrict__ obj,
        const float* __restrict__ cnorm, const float* __restrict__ onorm,
        float* __restrict__ sigc, float* __restrict__ sigo) {
    __shared__ float cv[NARG][DD];
    __shared__ float cn[NARG];
    const int tid = threadIdx.x;
    for (int a = 0; a < NARG; a++)
        for (int i = tid; i < DD; i += 256) cv[a][i] = ct[(size_t)a * DD + i];
    if (tid < NARG) cn[tid] = fmaxf(cnorm[tid], EPSC);
    __syncthreads();
    const int sub = tid & 7, slot = tid >> 3;
    #pragma unroll
    for (int p = 0; p < 8; p++) {
        const int r = blockIdx.x * 256 + p * 32 + slot;
        const float* row = (r < MC) ? (ct + (size_t)r * DD) : (obj + (size_t)(r - MC) * DD);
        float4 r0 = *(const float4*)(row + sub * 16 + 0);
        float4 r1 = *(const float4*)(row + sub * 16 + 4);
        float4 r2 = *(const float4*)(row + sub * 16 + 8);
        float4 r3 = *(const float4*)(row + sub * 16 + 12);
        float rn = fmaxf((r < MC) ? cnorm[r] : onorm[r - MC], EPSC);
        for (int a = 0; a < NARG; a++) {
            const float* c = &cv[a][sub * 16];
            float dp = 0.f;
            dp = fmaf(r0.x, c[0], dp);  dp = fmaf(r0.y, c[1], dp);
            dp = fmaf(r0.z, c[2], dp);  dp = fmaf(r0.w, c[3], dp);
            dp = fmaf(r1.x, c[4], dp);  dp = fmaf(r1.y, c[5], dp);
            dp = fmaf(r1.z, c[6], dp);  dp = fmaf(r1.w, c[7], dp);
            dp = fmaf(r2.x, c[8], dp);  dp = fmaf(r2.y, c[9], dp);
            dp = fmaf(r2.z, c[10], dp); dp = fmaf(r2.w, c[11], dp);
            dp = fmaf(r3.x, c[12], dp); dp = fmaf(r3.y, c[13], dp);
            dp = fmaf(r3.z, c[14], dp); dp = fmaf(r3.w, c[15], dp);
            dp += __shfl_xor(dp, 1, 64);
            dp += __shfl_xor(dp, 2, 64);
            dp += __shfl_xor(dp, 4, 64);
            if (sub == 0) {
                float sim = dp / (rn * cn[a]);
                float g = 1.f / (1.f + __expf(-(sim - THC) * TEMPC));
                if (r < MC) sigc[(size_t)a * MC + r] = g;
                else {
                    int ro = r - MC, bb = ro >> 7, oo = ro & 127;
                    sigo[((size_t)bb * NARG + a) * NOBJ + oo] = g;
                }
            }
        }
    }
}

// f32 fallback sim pass (only if a verify arg >= NARG ever appears)
__device__ __forceinline__ void sim_pass_f32(
        const float* __restrict__ ct, const float* __restrict__ myobj,
        const float* vec, const float* nrm, float* att,
        float vn, int tid, float* hrow) {
    const int sub = tid & 7, slot = tid >> 3;
    for (int n = slot; n < NN; n += 128) {
        const float* row = (n < MC) ? (ct + (size_t)n * DD)
                                    : (myobj + (size_t)(n - MC) * DD);
        float dp = 0.f;
        #pragma unroll
        for (int i = 0; i < 4; i++) {
            const float4 rv = *(const float4*)(row + sub * 16 + i * 4);
            const float4 vv = *(const float4*)(vec + sub * 16 + i * 4);
            dp = fmaf(rv.x, vv.x, dp); dp = fmaf(rv.y, vv.y, dp);
            dp = fmaf(rv.z, vv.z, dp); dp = fmaf(rv.w, vv.w, dp);
        }
        dp += __shfl_xor(dp, 1, 64);
        dp += __shfl_xor(dp, 2, 64);
        dp += __shfl_xor(dp, 4, 64);
        if (sub == 0) {
            float sim = dp / (fmaxf(nrm[n] * INV_FSCALE, EPSC) * vn);
            float g = 1.f / (1.f + __expf(-(sim - THC) * TEMPC));
            float nv = fminf(att[n], g);
            att[n] = nv; hrow[n] = nv;
        }
    }
}

// ---------------- Kernel D: per-sample program scan ----------------
__global__ __launch_bounds__(1024) void scan_exec(
        const float* __restrict__ ct, const float* __restrict__ rt,
        const int* __restrict__ program, const float* __restrict__ obj,
        const float* __restrict__ cnorm, const float* __restrict__ onorm,
        const float* __restrict__ sigc, const float* __restrict__ sigo,
        const unsigned char* __restrict__ ctf8, const unsigned char* __restrict__ objf8,
        float* __restrict__ out, float* __restrict__ hist) {
    const int b    = blockIdx.x;
    const int tid  = threadIdx.x;
    const int lane = tid & 63, wid = tid >> 6;
    __shared__ __align__(16) float att[NN];
    __shared__ __align__(16) float nrm[NN];        // FSCALE-scaled norms
    __shared__ __align__(16) float vec[DD];        // scaled trans
    __shared__ __align__(16) float gv[DD];         // scaled gather
    __shared__ __align__(16) float part[16 * DD];  // wave partials (8 KB)
    __shared__ float red[16];
    __shared__ float red2[16];
    __shared__ float redN[2];
    __shared__ int   sprog[2 * LL];
    const float*         myobj   = obj   + (size_t)b * NOBJ * DD;
    const unsigned char* myobjf8 = objf8 + (size_t)b * NOBJ * DD;

    for (int i = tid; i < NN; i += T) {
        att[i] = 1.0f;
        nrm[i] = FSCALE * ((i < MC) ? cnorm[i] : onorm[b * NOBJ + (i - MC)]);
    }
    if (tid < 2 * LL) sprog[tid] = program[b * 2 * LL + tid];
    __syncthreads();

    for (int step = 0; step < LL; step++) {
        const int op  = sprog[step * 2 + 0];
        const int arg = sprog[step * 2 + 1];
        float* hrow = hist + ((size_t)b * LL + step) * NN;

        if (op == 0) {                 // null: hist = att
            for (int i = tid; i < NN; i += T) hrow[i] = att[i];
        } else if (op == 1) {          // sel_obj
            for (int i = tid; i < NN; i += T) {
                float nv = (i < MC) ? 0.0f : att[i];
                att[i] = nv; hrow[i] = nv;
            }
        } else if (op == 2) {          // sel_con
            for (int i = tid; i < NN; i += T) {
                float nv = (i < MC) ? att[i] : 0.0f;
                att[i] = nv; hrow[i] = nv;
            }
        } else if (op == 3) {          // verify: table lookup
            if (arg < NARG) {
                const float* sc = sigc + (size_t)arg * MC;
                const float* so = sigo + ((size_t)b * NARG + arg) * NOBJ;
                for (int i = tid; i < NN; i += T) {
                    float g = (i < MC) ? sc[i] : so[i - MC];
                    float nv = fminf(att[i], g);
                    att[i] = nv; hrow[i] = nv;
                }
            } else {                   // robustness fallback (never hit for this data)
                if (tid < DD) vec[tid] = ct[(size_t)arg * DD + tid];
                __syncthreads();
                sim_pass_f32(ct, myobj, vec, nrm, att, fmaxf(cnorm[arg], EPSC), tid, hrow);
            }
        } else if (op == 4) {          // choose
            for (int i = tid; i < NN; i += T) {
                float nv = (i < MC) ? ((i == arg) ? 1.0f : 0.0f) : att[i];
                att[i] = nv; hrow[i] = nv;
            }
        } else if (op == 5) {          // exist
            float lm = NINF;
            for (int i = tid; i < NN; i += T) lm = fmaxf(lm, att[i]);
            #pragma unroll
            for (int off = 32; off; off >>= 1) lm = fmaxf(lm, __shfl_xor(lm, off, 64));
            if (lane == 0) red[wid] = lm;
            __syncthreads();
            float s = red[0];
            #pragma unroll
            for (int w = 1; w < 16; w++) s = fmaxf(s, red[w]);
            float yes = s * POSC;
            float no  = POSC - yes;
            for (int i = tid; i < NN; i += T) {
                float nv = (i == 0) ? yes : ((i == 1) ? no : NEGC);
                att[i] = nv; hrow[i] = nv;
            }
        } else if (op == 6) {          // transfer (fp8 sweeps, depth-2 pipeline)
            // ---- s = max(att) ----
            float lm = NINF;
            for (int i = tid; i < NN; i += T) lm = fmaxf(lm, att[i]);
            #pragma unroll
            for (int off = 32; off; off >>= 1) lm = fmaxf(lm, __shfl_xor(lm, off, 64));
            if (lane == 0) red[wid] = lm;
            __syncthreads();            // also guarantees att stable for gather
            float s = red[0];
            #pragma unroll
            for (int w = 1; w < 16; w++) s = fmaxf(s, red[w]);

            // ---- gather[d] = sum_n att[n] * node_s[n][d] ----
            const int sub   = tid & 7;          // 16 d's per thread
            const int rgrp  = tid >> 3;         // 0..127 row groups
            const int dbase = sub * 16;
            float ac[16];
            #pragma unroll
            for (int j = 0; j < 16; j++) ac[j] = 0.f;
            {
                #define ROWP(n) ((const uint4*)(((n) < MC ? ctf8 + (size_t)(n) * DD \
                                   : myobjf8 + (size_t)((n) - MC) * DD) + dbase))
                uint4 u0 = *ROWP(rgrp);
                uint4 u1 = *ROWP(rgrp + 128);
                #pragma unroll 4
                for (int p = 0; p < 17; p++) {
                    uint4 cur = u0;
                    u0 = u1;
                    if (p < 15) u1 = *ROWP(rgrp + (p + 2) * 128);
                    float a = att[rgrp + p * 128];
                    v2f g0 = F8LO(cur.x), g1 = F8HI(cur.x), g2 = F8LO(cur.y), g3 = F8HI(cur.y);
                    v2f g4 = F8LO(cur.z), g5 = F8HI(cur.z), g6 = F8LO(cur.w), g7 = F8HI(cur.w);
                    ac[0]  = fmaf(a, g0[0], ac[0]);  ac[1]  = fmaf(a, g0[1], ac[1]);
                    ac[2]  = fmaf(a, g1[0], ac[2]);  ac[3]  = fmaf(a, g1[1], ac[3]);
                    ac[4]  = fmaf(a, g2[0], ac[4]);  ac[5]  = fmaf(a, g2[1], ac[5]);
                    ac[6]  = fmaf(a, g3[0], ac[6]);  ac[7]  = fmaf(a, g3[1], ac[7]);
                    ac[8]  = fmaf(a, g4[0], ac[8]);  ac[9]  = fmaf(a, g4[1], ac[9]);
                    ac[10] = fmaf(a, g5[0], ac[10]); ac[11] = fmaf(a, g5[1], ac[11]);
                    ac[12] = fmaf(a, g6[0], ac[12]); ac[13] = fmaf(a, g6[1], ac[13]);
                    ac[14] = fmaf(a, g7[0], ac[14]); ac[15] = fmaf(a, g7[1], ac[15]);
                }
            }
            // cross-row-group reduce within wave (lanes differing in bits 3..5)
            #pragma unroll
            for (int j = 0; j < 16; j++) {
                ac[j] += __shfl_xor(ac[j], 8, 64);
                ac[j] += __shfl_xor(ac[j], 16, 64);
                ac[j] += __shfl_xor(ac[j], 32, 64);
            }
            if (lane < 8) {
                float* dst = &part[wid * DD + lane * 16];
                #pragma unroll
                for (int k = 0; k < 4; k++)
                    *(float4*)(dst + k * 4) = make_float4(ac[k*4], ac[k*4+1], ac[k*4+2], ac[k*4+3]);
            }
            __syncthreads();
            if (tid < DD) {
                float g = 0.f;
                #pragma unroll
                for (int w = 0; w < 16; w++) g += part[w * DD + tid];
                gv[tid] = g;
            }
            __syncthreads();

            // ---- trans[d'] = sum_d gv[d] * rmat[d][d'] ----
            const float* rm = rt + (size_t)arg * (DD * DD);
            const int grp = tid >> 5, dq = (tid & 31) * 4;
            float qx = 0.f, qy = 0.f, qz = 0.f, qw = 0.f;
            #pragma unroll
            for (int k = 0; k < 4; k++) {
                int d = grp + k * 32;
                float g = gv[d];
                const float4 r = *(const float4*)(rm + (size_t)d * DD + dq);
                qx = fmaf(g, r.x, qx); qy = fmaf(g, r.y, qy);
                qz = fmaf(g, r.z, qz); qw = fmaf(g, r.w, qw);
            }
            // pair-reduce across grp partner (lane ^ 32)
            qx += __shfl_xor(qx, 32, 64); qy += __shfl_xor(qy, 32, 64);
            qz += __shfl_xor(qz, 32, 64); qw += __shfl_xor(qw, 32, 64);
            if (lane < 32)
                *(float4*)&part[wid * DD + dq] = make_float4(qx, qy, qz, qw);
            __syncthreads();
            if (tid < DD) {
                float t = 0.f;
                #pragma unroll
                for (int w = 0; w < 16; w++) t += part[w * DD + tid];
                vec[tid] = t;
                float ss = t * t;
                #pragma unroll
                for (int off = 32; off; off >>= 1) ss += __shfl_xor(ss, off, 64);
                if (lane == 0) redN[wid] = ss;
            }
            __syncthreads();
            float tn = fmaxf(sqrtf(redN[0] + redN[1]), EPSC);

            // ---- sim pass over fp8 nodes; writes att + hist ----
            const int slot = tid >> 3;
            float vv[16];
            {
                const float4 v0 = *(const float4*)&vec[dbase];
                const float4 v1 = *(const float4*)&vec[dbase + 4];
                const float4 v2 = *(const float4*)&vec[dbase + 8];
                const float4 v3 = *(const float4*)&vec[dbase + 12];
                vv[0]=v0.x; vv[1]=v0.y; vv[2]=v0.z; vv[3]=v0.w;
                vv[4]=v1.x; vv[5]=v1.y; vv[6]=v1.z; vv[7]=v1.w;
                vv[8]=v2.x; vv[9]=v2.y; vv[10]=v2.z; vv[11]=v2.w;
                vv[12]=v3.x; vv[13]=v3.y; vv[14]=v3.z; vv[15]=v3.w;
            }
            {
                uint4 u0 = *ROWP(slot);
                uint4 u1 = *ROWP(slot + 128);
                #pragma unroll 4
                for (int p = 0; p < 17; p++) {
                    uint4 cur = u0;
                    u0 = u1;
                    if (p < 15) u1 = *ROWP(slot + (p + 2) * 128);
                    const int n = slot + p * 128;
                    v2f a0 = F8LO(cur.x), a1 = F8HI(cur.x), a2 = F8LO(cur.y), a3 = F8HI(cur.y);
                    v2f a4 = F8LO(cur.z), a5 = F8HI(cur.z), a6 = F8LO(cur.w), a7 = F8HI(cur.w);
                    float dp = 0.f;
                    dp = fmaf(a0[0], vv[0],  dp); dp = fmaf(a0[1], vv[1],  dp);
                    dp = fmaf(a1[0], vv[2],  dp); dp = fmaf(a1[1], vv[3],  dp);
                    dp = fmaf(a2[0], vv[4],  dp); dp = fmaf(a2[1], vv[5],  dp);
                    dp = fmaf(a3[0], vv[6],  dp); dp = fmaf(a3[1], vv[7],  dp);
                    dp = fmaf(a4[0], vv[8],  dp); dp = fmaf(a4[1], vv[9],  dp);
                    dp = fmaf(a5[0], vv[10], dp); dp = fmaf(a5[1], vv[11], dp);
                    dp = fmaf(a6[0], vv[12], dp); dp = fmaf(a6[1], vv[13], dp);
                    dp = fmaf(a7[0], vv[14], dp); dp = fmaf(a7[1], vv[15], dp);
                    dp += __shfl_xor(dp, 1, 64);
                    dp += __shfl_xor(dp, 2, 64);
                    dp += __shfl_xor(dp, 4, 64);
                    if (sub == 0) {
                        float sim = dp / (nrm[n] * tn);
                        float g = 1.f / (1.f + __expf(-(sim - THC) * TEMPC));
                        float nv = g * s;
                        att[n] = nv; hrow[n] = nv;
                    }
                }
                #undef ROWP
            }
        }

        __syncthreads();   // att stable for next step
    }

    // log_softmax over att[0:MC]
    float lm = NINF;
    for (int i = tid; i < MC; i += T) lm = fmaxf(lm, att[i]);
    #pragma unroll
    for (int off = 32; off; off >>= 1) lm = fmaxf(lm, __shfl_xor(lm, off, 64));
    if (lane == 0) red[wid] = lm;
    __syncthreads();
    float m = red[0];
    #pragma unroll
    for (int w = 1; w < 16; w++) m = fmaxf(m, red[w]);
    float lse = 0.f;
    for (int i = tid; i < MC; i += T) lse += expf(att[i] - m);
    #pragma unroll
    for (int off = 32; off; off >>= 1) lse += __shfl_xor(lse, off, 64);
    if (lane == 0) red2[wid] = lse;
    __syncthreads();
    float se = red2[0];
    #pragma unroll
    for (int w = 1; w < 16; w++) se += red2[w];
    float ls = logf(se);
    for (int i = tid; i < MC; i += T)
        out[(size_t)b * MC + i] = att[i] - m - ls;
}

extern "C" void kernel_launch(void* const* d_in, const int* in_sizes, int n_in,
                              void* d_out, int out_size, void* d_ws, size_t ws_size,
                              hipStream_t stream) {
    const float* scene = (const float*)d_in[0];
    const int*   prog  = (const int*)d_in[1];
    const float* ct    = (const float*)d_in[2];
    const float* rt    = (const float*)d_in[3];
    const float* W     = (const float*)d_in[4];
    const float* bias  = (const float*)d_in[5];

    float* out  = (float*)d_out;
    float* hist = out + (size_t)BB * MC;

    float* obj   = (float*)d_ws;                       // B*NOBJ*D f32
    float* cnorm = obj + (size_t)BB * NOBJ * DD;       // MC
    float* onorm = cnorm + MC;                         // B*NOBJ
    float* sigc  = onorm + (size_t)BB * NOBJ;          // NARG*MC
    float* sigo  = sigc + (size_t)NARG * MC;           // B*NARG*NOBJ
    unsigned char* ctf8  = (unsigned char*)(sigo + (size_t)BB * NARG * NOBJ);  // MC*DD bytes
    unsigned char* objf8 = ctf8 + (size_t)MC * DD;     // B*NOBJ*DD bytes

    gemm_objects<<<dim3(4, BB), 256, 0, stream>>>(scene, W, bias, obj);
    norms_prep<<<dim3((MC + BB * NOBJ) / 4), 256, 0, stream>>>(ct, obj, cnorm, onorm, ctf8, objf8);
    sig_table<<<dim3((MC + BB * NOBJ) / 256), 256, 0, stream>>>(ct, obj, cnorm, onorm, sigc, sigo);
    scan_exec<<<dim3(BB), 1024, 0, stream>>>(ct, rt, prog, obj, cnorm, onorm,
                                             sigc, sigo, ctf8, objf8, out, hist);
}